// Round 1
// baseline (2731.266 us; speedup 1.0000x reference)
//
#include <hip/hip_runtime.h>
#include <math.h>

#define TT 1024
#define BB 2
#define DD 1024
#define NH 16
#define NKV 4
#define HD 64
#define ED 4096
#define LL 4
#define VV 32000

typedef __bf16 bf16x8 __attribute__((ext_vector_type(8)));
typedef float f32x4 __attribute__((ext_vector_type(4)));

__device__ inline unsigned short f2bf(float f) {
  unsigned u = __float_as_uint(f);
  u += 0x7fffu + ((u >> 16) & 1u);   // round-to-nearest-even
  return (unsigned short)(u >> 16);
}

// ---------------- embedding gather ----------------
__global__ void embed_kernel(const int* __restrict__ ids, const float* __restrict__ emb,
                             float* __restrict__ x) {
  int row = blockIdx.x;
  int id = ids[row];
  const float4* src = (const float4*)(emb + (size_t)id * DD);
  float4* dst = (float4*)(x + (size_t)row * DD);
  dst[threadIdx.x] = src[threadIdx.x];
}

// ---------------- rmsnorm (fp32 in -> bf16 out) ----------------
__global__ __launch_bounds__(256) void rmsnorm_kernel(const float* __restrict__ x,
                                                      const float* __restrict__ wgt,
                                                      unsigned short* __restrict__ out) {
  int row = blockIdx.x;
  int tid = threadIdx.x;
  float4 v = *(const float4*)(x + (size_t)row * DD + tid * 4);
  float ss = v.x * v.x + v.y * v.y + v.z * v.z + v.w * v.w;
#pragma unroll
  for (int off = 32; off >= 1; off >>= 1) ss += __shfl_xor(ss, off);
  __shared__ float part[4];
  if ((tid & 63) == 0) part[tid >> 6] = ss;
  __syncthreads();
  ss = part[0] + part[1] + part[2] + part[3];
  float sc = rsqrtf(ss * (1.0f / DD) + 1e-6f);
  float4 wv = *(const float4*)(wgt + tid * 4);
  uint2 o;
  o.x = f2bf(v.x * wv.x * sc) | ((unsigned)f2bf(v.y * wv.y * sc) << 16);
  o.y = f2bf(v.z * wv.z * sc) | ((unsigned)f2bf(v.w * wv.w * sc) << 16);
  *(uint2*)(out + (size_t)row * DD + tid * 4) = o;
}

// ---------------- GEMM: C[M,N] (+)= A[M,K](bf16) * W[N,K]^T(fp32->bf16) ----------------
// EPI 0: store, EPI 1: accumulate into C (residual add)
template <int EPI>
__global__ __launch_bounds__(256) void gemm_bt(const unsigned short* __restrict__ A,
                                               const float* __restrict__ W,
                                               float* __restrict__ C, int M, int N, int K) {
  __shared__ unsigned short As[128 * 40];
  __shared__ unsigned short Bs[128 * 40];
  const int tid = threadIdx.x;
  const int lane = tid & 63;
  const int w = tid >> 6;
  const int wm = (w >> 1) * 64;
  const int wn = (w & 1) * 64;
  const int l15 = lane & 15;
  const int quad = lane >> 4;
  const int q8 = quad * 8;
  const int mBase = blockIdx.y * 128;
  const int nBase = blockIdx.x * 128;

  f32x4 acc[4][4] = {};

  for (int kt = 0; kt < K; kt += 32) {
    __syncthreads();
#pragma unroll
    for (int i = 0; i < 2; i++) {  // stage A (bf16 copy), 512 chunks of 8 elems
      int chunk = tid + 256 * i;
      int r = chunk >> 2, c8 = (chunk & 3) * 8;
      uint4 v = *(const uint4*)(A + (size_t)(mBase + r) * K + kt + c8);
      *(uint4*)&As[r * 40 + c8] = v;
    }
#pragma unroll
    for (int i = 0; i < 2; i++) {  // stage B with fp32->bf16 convert
      int chunk = tid + 256 * i;
      int r = chunk >> 2, c8 = (chunk & 3) * 8;
      const float4* wp = (const float4*)(W + (size_t)(nBase + r) * K + kt + c8);
      float4 f0 = wp[0], f1 = wp[1];
      uint4 v;
      v.x = f2bf(f0.x) | ((unsigned)f2bf(f0.y) << 16);
      v.y = f2bf(f0.z) | ((unsigned)f2bf(f0.w) << 16);
      v.z = f2bf(f1.x) | ((unsigned)f2bf(f1.y) << 16);
      v.w = f2bf(f1.z) | ((unsigned)f2bf(f1.w) << 16);
      *(uint4*)&Bs[r * 40 + c8] = v;
    }
    __syncthreads();
    bf16x8 af[4], bfv[4];
#pragma unroll
    for (int ms = 0; ms < 4; ms++)
      af[ms] = *(const bf16x8*)&As[(wm + ms * 16 + l15) * 40 + q8];
#pragma unroll
    for (int ns = 0; ns < 4; ns++)
      bfv[ns] = *(const bf16x8*)&Bs[(wn + ns * 16 + l15) * 40 + q8];
#pragma unroll
    for (int ms = 0; ms < 4; ms++)
#pragma unroll
      for (int ns = 0; ns < 4; ns++)
        acc[ms][ns] = __builtin_amdgcn_mfma_f32_16x16x32_bf16(af[ms], bfv[ns], acc[ms][ns], 0, 0, 0);
  }
#pragma unroll
  for (int ms = 0; ms < 4; ms++)
#pragma unroll
    for (int ns = 0; ns < 4; ns++)
#pragma unroll
      for (int r = 0; r < 4; r++) {
        int row = mBase + wm + ms * 16 + quad * 4 + r;
        int col = nBase + wn + ns * 16 + l15;
        size_t idx = (size_t)row * N + col;
        if (EPI == 0) C[idx] = acc[ms][ns][r];
        else C[idx] += acc[ms][ns][r];
      }
}

// ---------------- RoPE (in-place, fp32) ----------------
__global__ void rope_kernel(float* __restrict__ buf, int nh) {
  int e = blockIdx.x * blockDim.x + threadIdx.x;
  int per_row = nh * 32;
  int row = e / per_row;
  int rem = e - row * per_row;
  int hh = rem >> 5;
  int d = rem & 31;
  int t = row & (TT - 1);
  float invf = __expf(-(float)d * 0.28782313662f);  // 10000^(-d/32)
  float ang = (float)t * invf;
  float sv, cv;
  sincosf(ang, &sv, &cv);
  float* p = buf + (size_t)row * (nh * 64) + hh * 64 + d;
  float x1 = p[0], x2 = p[32];
  p[0] = x1 * cv - x2 * sv;
  p[32] = x2 * cv + x1 * sv;
}

// ---------------- flash attention (bf16 MFMA, fp32 softmax) ----------------
__global__ __launch_bounds__(256) void attn_fwd(const float* __restrict__ Q,
                                                const float* __restrict__ Kb,
                                                const float* __restrict__ Vb,
                                                unsigned short* __restrict__ O) {
  __shared__ unsigned short Qs[64 * 72];  // reused as P after Q frags are in regs
  __shared__ unsigned short Ks[64 * 72];
  __shared__ unsigned short Vt[64 * 72];  // transposed V: [d][key]
  const int tid = threadIdx.x;
  const int lane = tid & 63;
  const int w = tid >> 6;
  const int l15 = lane & 15;
  const int quad = lane >> 4;
  const int q8 = quad * 8;
  const int bh = blockIdx.x;
  const int b = bh / NH, h = bh % NH;
  const int hkv = h >> 2;
  const int qb = blockIdx.y;

#pragma unroll
  for (int i = 0; i < 4; i++) {  // stage Q tile 64x64
    int cc = tid + 256 * i;
    int r = cc >> 4, d4 = (cc & 15) * 4;
    float4 v = *(const float4*)(Q + (size_t)(b * TT + qb * 64 + r) * DD + h * HD + d4);
    uint2 p;
    p.x = f2bf(v.x) | ((unsigned)f2bf(v.y) << 16);
    p.y = f2bf(v.z) | ((unsigned)f2bf(v.w) << 16);
    *(uint2*)&Qs[r * 72 + d4] = p;
  }
  __syncthreads();
  bf16x8 qa0 = *(const bf16x8*)&Qs[(w * 16 + l15) * 72 + q8];
  bf16x8 qa1 = *(const bf16x8*)&Qs[(w * 16 + l15) * 72 + 32 + q8];

  f32x4 oacc[4] = {};
  float m_i[4], l_i[4];
#pragma unroll
  for (int r = 0; r < 4; r++) { m_i[r] = -1e30f; l_i[r] = 0.f; }

  for (int kb = 0; kb <= qb; kb++) {
    __syncthreads();
#pragma unroll
    for (int i = 0; i < 4; i++) {  // stage K (row-major) and V (transposed)
      int cc = tid + 256 * i;
      int r = cc >> 4, d4 = (cc & 15) * 4;
      size_t grow = (size_t)(b * TT + kb * 64 + r) * (NKV * HD) + hkv * HD + d4;
      float4 kv = *(const float4*)(Kb + grow);
      uint2 p;
      p.x = f2bf(kv.x) | ((unsigned)f2bf(kv.y) << 16);
      p.y = f2bf(kv.z) | ((unsigned)f2bf(kv.w) << 16);
      *(uint2*)&Ks[r * 72 + d4] = p;
      float4 vv = *(const float4*)(Vb + grow);
      Vt[(d4 + 0) * 72 + r] = f2bf(vv.x);
      Vt[(d4 + 1) * 72 + r] = f2bf(vv.y);
      Vt[(d4 + 2) * 72 + r] = f2bf(vv.z);
      Vt[(d4 + 3) * 72 + r] = f2bf(vv.w);
    }
    __syncthreads();
    // S = Q K^T : 16 q-rows x 64 keys per wave
    f32x4 s[4];
#pragma unroll
    for (int ns = 0; ns < 4; ns++) {
      bf16x8 k0 = *(const bf16x8*)&Ks[(ns * 16 + l15) * 72 + q8];
      bf16x8 k1 = *(const bf16x8*)&Ks[(ns * 16 + l15) * 72 + 32 + q8];
      f32x4 z = {};
      z = __builtin_amdgcn_mfma_f32_16x16x32_bf16(qa0, k0, z, 0, 0, 0);
      s[ns] = __builtin_amdgcn_mfma_f32_16x16x32_bf16(qa1, k1, z, 0, 0, 0);
    }
#pragma unroll
    for (int ns = 0; ns < 4; ns++)
#pragma unroll
      for (int r = 0; r < 4; r++) {
        float sv = s[ns][r] * 0.125f;  // 1/sqrt(64)
        if (kb == qb) {
          int qloc = w * 16 + quad * 4 + r;
          int kloc = ns * 16 + l15;
          if (kloc > qloc) sv = -1e30f;
        }
        s[ns][r] = sv;
      }
    // online softmax; row r lives in the 16-lane group (quad fixed)
    float p[4][4];
    float alpha[4];
#pragma unroll
    for (int r = 0; r < 4; r++) {
      float mx = fmaxf(fmaxf(s[0][r], s[1][r]), fmaxf(s[2][r], s[3][r]));
#pragma unroll
      for (int off = 1; off < 16; off <<= 1) mx = fmaxf(mx, __shfl_xor(mx, off));
      float mnew = fmaxf(m_i[r], mx);
      alpha[r] = __expf(m_i[r] - mnew);
      float rs = 0.f;
#pragma unroll
      for (int ns = 0; ns < 4; ns++) {
        p[ns][r] = __expf(s[ns][r] - mnew);
        rs += p[ns][r];
      }
#pragma unroll
      for (int off = 1; off < 16; off <<= 1) rs += __shfl_xor(rs, off);
      l_i[r] = l_i[r] * alpha[r] + rs;
      m_i[r] = mnew;
    }
#pragma unroll
    for (int ds = 0; ds < 4; ds++)
#pragma unroll
      for (int r = 0; r < 4; r++) oacc[ds][r] *= alpha[r];
    // P: C-layout regs -> LDS (A-layout read). Per-wave private 16-row strip.
#pragma unroll
    for (int ns = 0; ns < 4; ns++)
#pragma unroll
      for (int r = 0; r < 4; r++)
        Qs[(w * 16 + quad * 4 + r) * 72 + ns * 16 + l15] = f2bf(p[ns][r]);
    __syncthreads();
    bf16x8 pa0 = *(const bf16x8*)&Qs[(w * 16 + l15) * 72 + q8];
    bf16x8 pa1 = *(const bf16x8*)&Qs[(w * 16 + l15) * 72 + 32 + q8];
#pragma unroll
    for (int ds = 0; ds < 4; ds++) {
      bf16x8 v0 = *(const bf16x8*)&Vt[(ds * 16 + l15) * 72 + q8];
      bf16x8 v1 = *(const bf16x8*)&Vt[(ds * 16 + l15) * 72 + 32 + q8];
      oacc[ds] = __builtin_amdgcn_mfma_f32_16x16x32_bf16(pa0, v0, oacc[ds], 0, 0, 0);
      oacc[ds] = __builtin_amdgcn_mfma_f32_16x16x32_bf16(pa1, v1, oacc[ds], 0, 0, 0);
    }
  }
#pragma unroll
  for (int ds = 0; ds < 4; ds++)
#pragma unroll
    for (int r = 0; r < 4; r++) {
      int row = qb * 64 + w * 16 + quad * 4 + r;
      int col = h * HD + ds * 16 + l15;
      O[(size_t)(b * TT + row) * DD + col] = f2bf(oacc[ds][r] / l_i[r]);
    }
}

// ---------------- SwiGLU: out = bf16(silu(g) * u) ----------------
__global__ void swiglu_kernel(const float* __restrict__ G, const float* __restrict__ U,
                              unsigned short* __restrict__ out) {
  size_t i = (size_t)blockIdx.x * blockDim.x + threadIdx.x;
  float4 g = ((const float4*)G)[i];
  float4 u = ((const float4*)U)[i];
  float r0 = g.x / (1.f + __expf(-g.x)) * u.x;
  float r1 = g.y / (1.f + __expf(-g.y)) * u.y;
  float r2 = g.z / (1.f + __expf(-g.z)) * u.z;
  float r3 = g.w / (1.f + __expf(-g.w)) * u.w;
  uint2 o;
  o.x = f2bf(r0) | ((unsigned)f2bf(r1) << 16);
  o.y = f2bf(r2) | ((unsigned)f2bf(r3) << 16);
  ((uint2*)out)[i] = o;
}

extern "C" void kernel_launch(void* const* d_in, const int* in_sizes, int n_in,
                              void* d_out, int out_size, void* d_ws, size_t ws_size,
                              hipStream_t stream) {
  const int* ids = (const int*)d_in[0];
  const float* emb = (const float*)d_in[1];
  const float* ln1 = (const float*)d_in[2];
  const float* qw = (const float*)d_in[3];
  const float* kw = (const float*)d_in[4];
  const float* vw = (const float*)d_in[5];
  const float* ow = (const float*)d_in[6];
  const float* ln2 = (const float*)d_in[7];
  const float* w1 = (const float*)d_in[8];
  const float* w2 = (const float*)d_in[9];
  const float* w3 = (const float*)d_in[10];
  const float* lnf = (const float*)d_in[11];

  const int BT = BB * TT;  // 2048
  const size_t MB = 1024ull * 1024ull;
  char* ob = (char*)d_out;  // 262 MB; dead until final logits GEMM
  float* gbuf = (float*)ob;                          // 32 MB
  float* ubuf = (float*)(ob + 32 * MB);              // 32 MB
  unsigned short* hb2 = (unsigned short*)(ob + 64 * MB);  // 16 MB

  float* x;
  unsigned short* hb;
  float* qbuf;
  float* kbuf;
  float* vbuf;
  unsigned short* ao;
  char* wb = (char*)d_ws;
  if (ws_size >= 28 * MB) {
    x = (float*)wb;                          // 8 MB
    hb = (unsigned short*)(wb + 8 * MB);     // 4 MB
    qbuf = (float*)(wb + 12 * MB);           // 8 MB
    kbuf = (float*)(wb + 20 * MB);           // 2 MB
    vbuf = (float*)(wb + 22 * MB);           // 2 MB
    ao = (unsigned short*)(wb + 24 * MB);    // 4 MB
  } else {
    hb = (unsigned short*)wb;                // needs >= 4 MB ws
    x = (float*)(ob + 80 * MB);
    qbuf = (float*)(ob + 88 * MB);
    kbuf = (float*)(ob + 96 * MB);
    vbuf = (float*)(ob + 98 * MB);
    ao = (unsigned short*)(ob + 100 * MB);
  }

  embed_kernel<<<BT, 256, 0, stream>>>(ids, emb, x);
  for (int l = 0; l < LL; l++) {
    rmsnorm_kernel<<<BT, 256, 0, stream>>>(x, ln1 + l * DD, hb);
    gemm_bt<0><<<dim3(DD / 128, BT / 128), 256, 0, stream>>>(hb, qw + (size_t)l * DD * DD, qbuf, BT, DD, DD);
    gemm_bt<0><<<dim3((NKV * HD) / 128, BT / 128), 256, 0, stream>>>(hb, kw + (size_t)l * NKV * HD * DD, kbuf, BT, NKV * HD, DD);
    gemm_bt<0><<<dim3((NKV * HD) / 128, BT / 128), 256, 0, stream>>>(hb, vw + (size_t)l * NKV * HD * DD, vbuf, BT, NKV * HD, DD);
    rope_kernel<<<(BT * NH * 32) / 256, 256, 0, stream>>>(qbuf, NH);
    rope_kernel<<<(BT * NKV * 32) / 256, 256, 0, stream>>>(kbuf, NKV);
    attn_fwd<<<dim3(BB * NH, TT / 64), 256, 0, stream>>>(qbuf, kbuf, vbuf, ao);
    gemm_bt<1><<<dim3(DD / 128, BT / 128), 256, 0, stream>>>(ao, ow + (size_t)l * DD * DD, x, BT, DD, DD);
    rmsnorm_kernel<<<BT, 256, 0, stream>>>(x, ln2 + l * DD, hb);
    gemm_bt<0><<<dim3(ED / 128, BT / 128), 256, 0, stream>>>(hb, w1 + (size_t)l * ED * DD, gbuf, BT, ED, DD);
    gemm_bt<0><<<dim3(ED / 128, BT / 128), 256, 0, stream>>>(hb, w3 + (size_t)l * ED * DD, ubuf, BT, ED, DD);
    swiglu_kernel<<<(BT * ED / 4) / 256, 256, 0, stream>>>(gbuf, ubuf, hb2);
    gemm_bt<1><<<dim3(DD / 128, BT / 128), 256, 0, stream>>>(hb2, w2 + (size_t)l * DD * ED, x, BT, DD, ED);
  }
  rmsnorm_kernel<<<BT, 256, 0, stream>>>(x, lnf, hb);
  gemm_bt<0><<<dim3(VV / 128, BT / 128), 256, 0, stream>>>(hb, emb, (float*)d_out, BT, VV, DD);
}